// Round 7
// baseline (154.458 us; speedup 1.0000x reference)
//
#include <hip/hip_runtime.h>
#include <math.h>

// Problem constants
#define NHEADS   64
#define TLEN     4096
#define CHUNK    16
#define NCHUNK   256  // TLEN / CHUNK

typedef unsigned short u16;
typedef unsigned int   u32;
typedef __attribute__((ext_vector_type(8))) short bf16x8;   // 8 bf16 in 4 VGPRs
typedef __attribute__((ext_vector_type(4))) float f32x4;

__device__ __forceinline__ u16 f2bf(float x) {               // RNE f32->bf16
    u32 u = __float_as_uint(x);
    u32 r = (u + 0x7FFFu + ((u >> 16) & 1u)) >> 16;
    return (u16)r;
}
__device__ __forceinline__ float bf2f(u16 h) { return __uint_as_float(((u32)h) << 16); }
__device__ __forceinline__ u16 f2bf_trunc(float x) { return (u16)(__float_as_uint(x) >> 16); }

// ws layout (BYTE offsets)
//  params f32 : 0        (gamma @4096, theta @4160, norm @4416)
//  W1pk  u16  : 32768    512 rows x (512 hi + 512 lo)          (1 MB)
//  CEpk  u16  : 1081344  512 rows x (512 hi + 512 lo)          (1 MB)
//  U     f32  : 10518528 4096 x 512 (scanned local states)     (8 MB)
//  E     f32  : 18907136 256 x 512                             (512 KB)
//  S     f32  : 19431424 256 x 512                             (512 KB)

// ---------------------------------------------------------------------------
// Kernel 1: one block per head. Setup (trace, gamma, theta, norm, expm of
// skew(P) via fp64 scaling-and-squaring Taylor) + fold Pm into B -> W1pk rows
// and into C -> CEpk column-slices (the old k_proj, now per-head local).
__global__ void k_pre(const float* __restrict__ P,
                      const float* __restrict__ Bmat,
                      const float* __restrict__ C,
                      const float* __restrict__ theta_log,
                      const float* __restrict__ gamma_log,
                      float* __restrict__ ws,
                      u16* __restrict__ W1pk,
                      u16* __restrict__ CEpk) {
    __shared__ float  Bsh[8*512];      // this head's 8 B-rows (16 KB)
    __shared__ float  Pf[64];          // expm result as float
    __shared__ double As[8][8];
    __shared__ double Rs[8][8];
    __shared__ double red[256];
    __shared__ int    sh_s;
    __shared__ float  sh_nrm;
    const int h = blockIdx.x;
    const int tid = threadIdx.x;
    const int i = (tid & 63) >> 3, j = tid & 7;
    const bool act = tid < 64;

    if (act)
        As[i][j] = (double)P[(h*8 + i)*8 + j] - (double)P[(h*8 + j)*8 + i];

    // stage B rows + trace(B B^T)
    const float* Bh = Bmat + h*8*512;
    double ss = 0.0;
    #pragma unroll
    for (int q = 0; q < 16; ++q) {
        float v = Bh[q*256 + tid];
        Bsh[q*256 + tid] = v;
        ss += (double)v * (double)v;
    }
    red[tid] = ss;
    __syncthreads();

    if (tid == 0) {
        double nrm = 0.0;
        for (int r = 0; r < 8; ++r) {
            double rs = 0.0;
            for (int c = 0; c < 8; ++c) rs += fabs(As[r][c]);
            nrm = fmax(nrm, rs);
        }
        int s = 0;
        while (nrm > 0.25 && s < 40) { nrm *= 0.5; ++s; }
        sh_s = s;
        double tr = 0.0;
        for (int q = 0; q < 256; ++q) tr += red[q];
        double ed = exp((double)gamma_log[h]);
        double g  = exp(-ed);
        ws[4096 + h] = (float)g;
        float nf = (float)sqrt((1.0 - g*g) / tr);
        ws[4416 + h] = nf;
        sh_nrm = nf;
    }
    if (tid < 4) ws[4160 + h*4 + tid] = expf(theta_log[h*4 + tid]);
    __syncthreads();

    const int NT = 13;
    if (act) {
        const double sc = ldexp(1.0, -sh_s);
        As[i][j] *= sc;
        Rs[i][j] = (i == j ? 1.0 : 0.0) + As[i][j] / (double)NT;
    }
    __syncthreads();
    for (int k = NT - 1; k >= 1; --k) {
        double t = 0.0;
        if (act) {
            #pragma unroll
            for (int m = 0; m < 8; ++m) t += As[i][m] * Rs[m][j];
        }
        __syncthreads();
        if (act) Rs[i][j] = (i == j ? 1.0 : 0.0) + t / (double)k;
        __syncthreads();
    }
    const int nsq = sh_s;
    for (int q = 0; q < nsq; ++q) {
        double t = 0.0;
        if (act) {
            #pragma unroll
            for (int m = 0; m < 8; ++m) t += Rs[i][m] * Rs[m][j];
        }
        __syncthreads();
        if (act) Rs[i][j] = t;
        __syncthreads();
    }
    if (act) Pf[i*8 + j] = (float)Rs[i][j];
    __syncthreads();

    const float nrmf = sh_nrm;
    // ---- W1 rows k = 8h+N:  W1[k][d] = nrm * sum_n Pm[N][n] * B[n][d] ----
    // thread owns d = 2*tid, 2*tid+1
    {
        const int d0 = 2*tid;
        #pragma unroll
        for (int N = 0; N < 8; ++N) {
            float a0 = 0.f, a1 = 0.f;
            #pragma unroll
            for (int n = 0; n < 8; ++n) {
                const float pm = Pf[N*8 + n];
                a0 += pm * Bsh[n*512 + d0];
                a1 += pm * Bsh[n*512 + d0 + 1];
            }
            a0 *= nrmf; a1 *= nrmf;
            u16 h0 = f2bf(a0), h1 = f2bf(a1);
            u16 l0 = f2bf_trunc(a0 - bf2f(h0)), l1 = f2bf_trunc(a1 - bf2f(h1));
            u16* base = W1pk + (size_t)(8*h + N)*1024;
            *reinterpret_cast<u32*>(base + d0)       = (u32)h0 | ((u32)h1 << 16);
            *reinterpret_cast<u32*>(base + 512 + d0) = (u32)l0 | ((u32)l1 << 16);
        }
    }
    // ---- CE column-slice: CE[e][8h+N] = sum_n Pm[N][n] * C[e][8h+n] ----
    // thread owns e = tid and e = tid+256
    #pragma unroll
    for (int ee = 0; ee < 2; ++ee) {
        const int e = ee*256 + tid;
        float4 c0 = *reinterpret_cast<const float4*>(C + (size_t)e*512 + 8*h);
        float4 c1 = *reinterpret_cast<const float4*>(C + (size_t)e*512 + 8*h + 4);
        float cv[8] = {c0.x, c0.y, c0.z, c0.w, c1.x, c1.y, c1.z, c1.w};
        u16 hv[8], lv[8];
        #pragma unroll
        for (int N = 0; N < 8; ++N) {
            float acc = 0.f;
            #pragma unroll
            for (int n = 0; n < 8; ++n) acc += Pf[N*8 + n] * cv[n];
            hv[N] = f2bf(acc);
            lv[N] = f2bf_trunc(acc - bf2f(hv[N]));
        }
        u16* base = CEpk + (size_t)e*1024 + 8*h;
        uint4 wh; wh.x = (u32)hv[0] | ((u32)hv[1] << 16); wh.y = (u32)hv[2] | ((u32)hv[3] << 16);
                  wh.z = (u32)hv[4] | ((u32)hv[5] << 16); wh.w = (u32)hv[6] | ((u32)hv[7] << 16);
        uint4 wl; wl.x = (u32)lv[0] | ((u32)lv[1] << 16); wl.y = (u32)lv[2] | ((u32)lv[3] << 16);
                  wl.z = (u32)lv[4] | ((u32)lv[5] << 16); wl.w = (u32)lv[6] | ((u32)lv[7] << 16);
        *reinterpret_cast<uint4*>(base)       = wh;
        *reinterpret_cast<uint4*>(base + 512) = wl;
    }
}

// ---------------------------------------------------------------------------
// Kernel 2/4: split-bf16 MFMA GEMM, 64x64 tile, 4 waves 2x2, BK=64, LDS dbuf.
// MODE 0: A = X transposed+split ON THE FLY during staging (no XT pass);
//         epilogue = in-LDS local scan -> U + E.
// MODE 1: A = U f32 + carry fixup during staging; epilogue = +D*x (X direct).
#define MFMA_BF16(A_, B_, C_) __builtin_amdgcn_mfma_f32_16x16x32_bf16(A_, B_, C_, 0, 0, 0)
template<int MODE>
__global__ __launch_bounds__(256, 2) void k_gemm(const float* __restrict__ Xf,
                                                 const float* __restrict__ Af,
                                                 const u16* __restrict__ Bpk,
                                                 float* __restrict__ Cout,
                                                 const float* __restrict__ Dvec,
                                                 const float* __restrict__ wsro,
                                                 float* __restrict__ E,
                                                 const float* __restrict__ S,
                                                 const float* __restrict__ TAB) {
    __shared__ char smem[73728];              // 2 x (Ah,Al,Bh,Bl of 9216 B)
    float* Ut = (float*)smem;                 // MODE0 epilogue scratch (18432 B)

    const int tid = threadIdx.x;
    const int bid = blockIdx.x;
    const int tile = (bid & 7) * 64 + (bid >> 3);   // XCD-chunked swizzle
    const int mt = tile >> 3, nt = tile & 7;
    const int m0 = mt * 64, n0 = nt * 64;
    const int lane = tid & 63, wid = tid >> 6;
    const int wm = wid >> 1, wn = wid & 1;
    const int lr = lane & 15, lc = lane >> 4;
    const int sr = tid >> 2, ss = (tid & 3) * 16;   // B staging: row, 16-elem seg
    const int tgrp4 = (tid & 15) * 4;               // MODE0 A staging: t offset
    const int dgrp4 = (tid >> 4) * 4;               // MODE0 A staging: d offset

    f32x4 acc00 = {0.f,0.f,0.f,0.f}, acc01 = acc00, acc10 = acc00, acc11 = acc00;

    const int tA = m0 + sr;                 // MODE1 staging row (t index)
    const int cA = tA >> 4, iA = tA & 15;   // chunk, offset (MODE1 fix)
    const u16* Brow = Bpk + (size_t)(n0 + sr)*1024 + ss;
    const float* Urow = (MODE == 1) ? (Af + (size_t)tA*512 + ss) : (const float*)0;

    float4 rb0, rb1, rb2, rb3;              // B prefetch regs
    float4 rx0, rx1, rx2, rx3;              // MODE0 A prefetch (4 d-rows x 4 t)
    float4 ru[4], rtb[4], rsv[4];           // MODE1 A prefetch

    auto LOADREGS = [&](int k0) {
        rb0 = *reinterpret_cast<const float4*>(Brow + k0);
        rb1 = *reinterpret_cast<const float4*>(Brow + k0 + 8);
        rb2 = *reinterpret_cast<const float4*>(Brow + 512 + k0);
        rb3 = *reinterpret_cast<const float4*>(Brow + 512 + k0 + 8);
        if constexpr (MODE == 0) {
            const float* Xc = Xf + (size_t)(k0 + dgrp4)*4096 + m0 + tgrp4;
            rx0 = *reinterpret_cast<const float4*>(Xc);
            rx1 = *reinterpret_cast<const float4*>(Xc + 4096);
            rx2 = *reinterpret_cast<const float4*>(Xc + 8192);
            rx3 = *reinterpret_cast<const float4*>(Xc + 12288);
        } else {
            const int p0 = (k0 + ss) >> 1;
            #pragma unroll
            for (int j = 0; j < 4; ++j) {
                ru[j]  = *reinterpret_cast<const float4*>(Urow + k0 + 4*j);
                rtb[j] = *reinterpret_cast<const float4*>(TAB + ((size_t)iA*256 + p0 + 2*j)*2);
                rsv[j] = *reinterpret_cast<const float4*>(S + (size_t)cA*512 + 2*p0 + 4*j);
            }
        }
    };
    auto STORE = [&](u16* Ah, u16* Al, u16* Bh, u16* Bl) {
        if constexpr (MODE == 0) {
            const float* r0 = &rx0.x;
            const float* r1 = &rx1.x;
            const float* r2 = &rx2.x;
            const float* r3 = &rx3.x;
            #pragma unroll
            for (int tt = 0; tt < 4; ++tt) {
                float a0 = r0[tt], a1 = r1[tt], a2 = r2[tt], a3 = r3[tt];
                u16 h0 = f2bf(a0), h1 = f2bf(a1), h2 = f2bf(a2), h3 = f2bf(a3);
                u16 l0 = f2bf_trunc(a0 - bf2f(h0)), l1 = f2bf_trunc(a1 - bf2f(h1));
                u16 l2 = f2bf_trunc(a2 - bf2f(h2)), l3 = f2bf_trunc(a3 - bf2f(h3));
                uint2 wh; wh.x = (u32)h0 | ((u32)h1 << 16); wh.y = (u32)h2 | ((u32)h3 << 16);
                uint2 wl; wl.x = (u32)l0 | ((u32)l1 << 16); wl.y = (u32)l2 | ((u32)l3 << 16);
                *reinterpret_cast<uint2*>(&Ah[(tgrp4 + tt)*72 + dgrp4]) = wh;
                *reinterpret_cast<uint2*>(&Al[(tgrp4 + tt)*72 + dgrp4]) = wl;
            }
        } else {
            #pragma unroll
            for (int j = 0; j < 4; ++j) {
                float4 u = ru[j], tb = rtb[j], sv = rsv[j];
                u.x += tb.x*sv.x - tb.y*sv.y;
                u.y += tb.y*sv.x + tb.x*sv.y;
                u.z += tb.z*sv.z - tb.w*sv.w;
                u.w += tb.w*sv.z + tb.z*sv.w;
                u16 hx = f2bf(u.x), hy = f2bf(u.y), hz = f2bf(u.z), hw = f2bf(u.w);
                u16 lx = f2bf_trunc(u.x - bf2f(hx)), ly = f2bf_trunc(u.y - bf2f(hy));
                u16 lz = f2bf_trunc(u.z - bf2f(hz)), lw = f2bf_trunc(u.w - bf2f(hw));
                uint2 wh; wh.x = (u32)hx | ((u32)hy << 16); wh.y = (u32)hz | ((u32)hw << 16);
                uint2 wl; wl.x = (u32)lx | ((u32)ly << 16); wl.y = (u32)lz | ((u32)lw << 16);
                *reinterpret_cast<uint2*>(&Ah[sr*72 + ss + 4*j]) = wh;
                *reinterpret_cast<uint2*>(&Al[sr*72 + ss + 4*j]) = wl;
            }
        }
        *reinterpret_cast<float4*>(&Bh[sr*72 + ss])     = rb0;
        *reinterpret_cast<float4*>(&Bh[sr*72 + ss + 8]) = rb1;
        *reinterpret_cast<float4*>(&Bl[sr*72 + ss])     = rb2;
        *reinterpret_cast<float4*>(&Bl[sr*72 + ss + 8]) = rb3;
    };
    auto MFMAS = [&](const u16* Ah, const u16* Al, const u16* Bh, const u16* Bl) {
        #pragma unroll
        for (int kk = 0; kk < 2; ++kk) {
            const int ko = kk*32 + lc*8;
            const int ra0i = (wm*32 + lr)*72 + ko,  ra1i = ra0i + 16*72;
            const int rb0i = (wn*32 + lr)*72 + ko,  rb1i = rb0i + 16*72;
            bf16x8 fah0 = *reinterpret_cast<const bf16x8*>(&Ah[ra0i]);
            bf16x8 fah1 = *reinterpret_cast<const bf16x8*>(&Ah[ra1i]);
            bf16x8 fal0 = *reinterpret_cast<const bf16x8*>(&Al[ra0i]);
            bf16x8 fal1 = *reinterpret_cast<const bf16x8*>(&Al[ra1i]);
            bf16x8 fbh0 = *reinterpret_cast<const bf16x8*>(&Bh[rb0i]);
            bf16x8 fbh1 = *reinterpret_cast<const bf16x8*>(&Bh[rb1i]);
            bf16x8 fbl0 = *reinterpret_cast<const bf16x8*>(&Bl[rb0i]);
            bf16x8 fbl1 = *reinterpret_cast<const bf16x8*>(&Bl[rb1i]);
            acc00 = MFMA_BF16(fah0, fbl0, acc00);
            acc00 = MFMA_BF16(fal0, fbh0, acc00);
            acc00 = MFMA_BF16(fah0, fbh0, acc00);
            acc01 = MFMA_BF16(fah0, fbl1, acc01);
            acc01 = MFMA_BF16(fal0, fbh1, acc01);
            acc01 = MFMA_BF16(fah0, fbh1, acc01);
            acc10 = MFMA_BF16(fah1, fbl0, acc10);
            acc10 = MFMA_BF16(fal1, fbh0, acc10);
            acc10 = MFMA_BF16(fah1, fbh0, acc10);
            acc11 = MFMA_BF16(fah1, fbl1, acc11);
            acc11 = MFMA_BF16(fal1, fbh1, acc11);
            acc11 = MFMA_BF16(fah1, fbh1, acc11);
        }
    };

    u16* buf0 = (u16*)smem;
    u16* buf1 = (u16*)(smem + 36864);

    LOADREGS(0);
    STORE(buf0, buf0 + 4608, buf0 + 9216, buf0 + 13824);
    __syncthreads();

    #pragma unroll
    for (int s = 0; s < 8; ++s) {
        u16* bp = (s & 1) ? buf1 : buf0;
        u16* bq = (s & 1) ? buf0 : buf1;
        if (s < 7) LOADREGS((s + 1) * 64);
        MFMAS(bp, bp + 4608, bp + 9216, bp + 13824);
        if (s < 7) STORE(bq, bq + 4608, bq + 9216, bq + 13824);
        __syncthreads();
    }

    if constexpr (MODE == 0) {
        // ---- fused local scan epilogue ----
        #pragma unroll
        for (int im = 0; im < 2; ++im) {
            #pragma unroll
            for (int in = 0; in < 2; ++in) {
                f32x4 v = (im == 0) ? (in == 0 ? acc00 : acc01)
                                    : (in == 0 ? acc10 : acc11);
                const int row0 = wm*32 + im*16 + lc*4;
                const int col  = wn*32 + in*16 + lr;
                #pragma unroll
                for (int rg = 0; rg < 4; ++rg)
                    Ut[(row0 + rg)*72 + col] = v[rg];
            }
        }
        __syncthreads();
        if (tid < 128) {
            const int cc = tid >> 5, pp = tid & 31;   // local chunk 0..3, local pair
            const int pg = nt*32 + pp;                // global pair
            const float th = wsro[4160 + pg];
            const float g  = wsro[4096 + (pg >> 2)];
            const float cs = cosf(th), sn = sinf(th);
            float h0 = 0.f, h1 = 0.f;
            float* col = Ut + (cc*16)*72 + 2*pp;
            #pragma unroll
            for (int i = 0; i < CHUNK; ++i) {
                float a = col[i*72], b = col[i*72 + 1];
                float n0v = g*(cs*h0 - sn*h1) + a;
                float n1v = g*(sn*h0 + cs*h1) + b;
                col[i*72] = n0v; col[i*72 + 1] = n1v;
                h0 = n0v; h1 = n1v;
            }
            E[(size_t)(mt*4 + cc)*512 + 2*pg]     = h0;
            E[(size_t)(mt*4 + cc)*512 + 2*pg + 1] = h1;
        }
        __syncthreads();
        const int row = tid >> 2, cseg = (tid & 3) * 16;
        #pragma unroll
        for (int j = 0; j < 4; ++j) {
            float4 v = *reinterpret_cast<const float4*>(&Ut[row*72 + cseg + 4*j]);
            *reinterpret_cast<float4*>(Cout + (size_t)(m0 + row)*512 + n0 + cseg + 4*j) = v;
        }
    } else {
        // ---- D*x epilogue, X read directly (wave reads full 64B lines) ----
        #pragma unroll
        for (int im = 0; im < 2; ++im) {
            #pragma unroll
            for (int in = 0; in < 2; ++in) {
                f32x4 v = (im == 0) ? (in == 0 ? acc00 : acc01)
                                    : (in == 0 ? acc10 : acc11);
                const int row0 = m0 + wm*32 + im*16 + lc*4;
                const int col  = n0 + wn*32 + in*16 + lr;
                const float dv = Dvec[col];
                float4 xv = *reinterpret_cast<const float4*>(Xf + (size_t)col*4096 + row0);
                const float* xp = &xv.x;
                #pragma unroll
                for (int rg = 0; rg < 4; ++rg)
                    Cout[(size_t)(row0 + rg)*512 + col] = v[rg] + dv * xp[rg];
            }
        }
    }
}

// ---------------------------------------------------------------------------
// Kernel 3: wave-parallel carry. One wave per pair p; lane l owns chunks
// 4l..4l+3. Chunk-step operator L = gamma^16 R(16*theta); scan multipliers
// L^{4*2^d} computed in closed form (fp64). Also emits TAB in closed form.
__global__ void k_carry(const float* __restrict__ E, float* __restrict__ S,
                        float* __restrict__ TAB,
                        const float* __restrict__ theta_log,
                        const float* __restrict__ gamma_log) {
    const int w = threadIdx.x >> 6, l = threadIdx.x & 63;
    const int p = blockIdx.x*4 + w;
    const double th = exp((double)theta_log[p]);
    const double ed = exp((double)gamma_log[p >> 2]);

    if (l < CHUNK) {   // TAB[i] = gamma^{i+1} * (cos,sin)((i+1)theta)
        double a = (double)(l + 1) * th;
        double g = exp(-(double)(l + 1) * ed);
        TAB[((size_t)l*256 + p)*2 + 0] = (float)(g * cos(a));
        TAB[((size_t)l*256 + p)*2 + 1] = (float)(g * sin(a));
    }

    const double a16 = 16.0*th, g16 = exp(-16.0*ed);
    const float Lc = (float)(g16*cos(a16)), Ls = (float)(g16*sin(a16));

    const float* Ep = E + 2*p;
    float2 e0 = *reinterpret_cast<const float2*>(Ep + (size_t)(4*l + 0)*512);
    float2 e1 = *reinterpret_cast<const float2*>(Ep + (size_t)(4*l + 1)*512);
    float2 e2 = *reinterpret_cast<const float2*>(Ep + (size_t)(4*l + 2)*512);
    float2 e3 = *reinterpret_cast<const float2*>(Ep + (size_t)(4*l + 3)*512);

    float2 v = e0;
    v = make_float2(Lc*v.x - Ls*v.y + e1.x, Ls*v.x + Lc*v.y + e1.y);
    v = make_float2(Lc*v.x - Ls*v.y + e2.x, Ls*v.x + Lc*v.y + e2.y);
    v = make_float2(Lc*v.x - Ls*v.y + e3.x, Ls*v.x + Lc*v.y + e3.y);

    #pragma unroll
    for (int d = 0; d < 6; ++d) {
        const int sh = 1 << d;
        const double aa = 64.0 * (double)sh * th;
        const double gg = exp(-64.0 * (double)sh * ed);
        const float Mc = (float)(gg*cos(aa)), Ms = (float)(gg*sin(aa));
        float px = __shfl_up(v.x, sh, 64);
        float py = __shfl_up(v.y, sh, 64);
        if (l >= sh) {
            v.x += Mc*px - Ms*py;
            v.y += Ms*px + Mc*py;
        }
    }

    float sx = __shfl_up(v.x, 1, 64), sy = __shfl_up(v.y, 1, 64);
    float2 s = (l == 0) ? make_float2(0.f, 0.f) : make_float2(sx, sy);
    float* Sp = S + 2*p;
    *reinterpret_cast<float2*>(Sp + (size_t)(4*l + 0)*512) = s;
    s = make_float2(Lc*s.x - Ls*s.y + e0.x, Ls*s.x + Lc*s.y + e0.y);
    *reinterpret_cast<float2*>(Sp + (size_t)(4*l + 1)*512) = s;
    s = make_float2(Lc*s.x - Ls*s.y + e1.x, Ls*s.x + Lc*s.y + e1.y);
    *reinterpret_cast<float2*>(Sp + (size_t)(4*l + 2)*512) = s;
    s = make_float2(Lc*s.x - Ls*s.y + e2.x, Ls*s.x + Lc*s.y + e2.y);
    *reinterpret_cast<float2*>(Sp + (size_t)(4*l + 3)*512) = s;
}

// ---------------------------------------------------------------------------
extern "C" void kernel_launch(void* const* d_in, const int* in_sizes, int n_in,
                              void* d_out, int out_size, void* d_ws, size_t ws_size,
                              hipStream_t stream) {
    const float* X  = (const float*)d_in[0];  // (8,1,512,1,4096); batch 0 = first 2M floats
    const float* th = (const float*)d_in[1];
    const float* P  = (const float*)d_in[2];
    const float* Bm = (const float*)d_in[3];
    const float* C  = (const float*)d_in[4];
    const float* Dv = (const float*)d_in[5];
    const float* gl = (const float*)d_in[6];
    char* wsb = (char*)d_ws;
    float* ws   = (float*)wsb;
    u16*   W1pk = (u16*)(wsb + 32768);
    u16*   CEpk = (u16*)(wsb + 1081344);
    float* U    = (float*)(wsb + 10518528);
    float* E    = (float*)(wsb + 18907136);
    float* S    = (float*)(wsb + 19431424);
    float* TAB  = (float*)(wsb + 19955712);
    float* out  = (float*)d_out;

    k_pre<<<NHEADS, 256, 0, stream>>>(P, Bm, C, th, gl, ws, W1pk, CEpk);
    k_gemm<0><<<512, 256, 0, stream>>>(X, (const float*)0, W1pk, U, Dv, ws, E, S, TAB);
    k_carry<<<64, 256, 0, stream>>>(E, S, TAB, th, gl);
    k_gemm<1><<<512, 256, 0, stream>>>(X, U, CEpk, out, Dv, ws, E, S, TAB);
}

// Round 8
// 152.520 us; speedup vs baseline: 1.0127x; 1.0127x over previous
//
#include <hip/hip_runtime.h>
#include <math.h>

// Problem constants
#define NHEADS   64
#define TLEN     4096
#define CHUNK    16
#define NCHUNK   256  // TLEN / CHUNK

typedef unsigned short u16;
typedef unsigned int   u32;
typedef __attribute__((ext_vector_type(8))) short bf16x8;   // 8 bf16 in 4 VGPRs
typedef __attribute__((ext_vector_type(4))) float f32x4;

__device__ __forceinline__ u16 f2bf(float x) {               // RNE f32->bf16
    u32 u = __float_as_uint(x);
    u32 r = (u + 0x7FFFu + ((u >> 16) & 1u)) >> 16;
    return (u16)r;
}
__device__ __forceinline__ float bf2f(u16 h) { return __uint_as_float(((u32)h) << 16); }
__device__ __forceinline__ u16 f2bf_trunc(float x) { return (u16)(__float_as_uint(x) >> 16); }

// ws layout (BYTE offsets)
//  params f32 : 0        (gamma @4096, theta @4160, norm @4416)
//  W1pk  u16  : 32768    512 rows x (512 hi + 512 lo)          (1 MB)
//  CEpk  u16  : 1081344  512 rows x (512 hi + 512 lo)          (1 MB)
//  XTpk  u16  : 2129920  4096 rows x (512 hi + 512 lo)         (8 MB)
//  U     f32  : 10518528 4096 x 512 (scanned local states)     (8 MB)
//  E     f32  : 18907136 256 x 512                             (512 KB)
//  S     f32  : 19431424 256 x 512                             (512 KB)
//  TAB   f32  : 19955712 16 x 256 x 2                          (32 KB)

// ---------------------------------------------------------------------------
// Kernel 1 (merged): blocks 0..511 transpose+pack X -> XTpk; blocks 512..575
// per-head setup (trace, gamma, theta, norm, expm of skew(P) in fp64) PLUS
// the Pm-fold into B -> W1pk and C -> CEpk (old k_proj, now per-head local).
__global__ void k_pre(const float* __restrict__ X, u16* __restrict__ XT,
                      const float* __restrict__ P,
                      const float* __restrict__ Bmat,
                      const float* __restrict__ C,
                      const float* __restrict__ theta_log,
                      const float* __restrict__ gamma_log,
                      float* __restrict__ ws,
                      u16* __restrict__ W1pk,
                      u16* __restrict__ CEpk) {
    const int tid = threadIdx.x;
    if (blockIdx.x < 512) {
        // ---- X[d][t] -> XTpk[t]{hi[512],lo[512]} ----
        __shared__ float Xs[64][65];
        const int t0 = (blockIdx.x & 63) * 64, d0 = (blockIdx.x >> 6) * 64;
        {
            const int dr = tid >> 4, tc = (tid & 15) * 4;
            #pragma unroll
            for (int it = 0; it < 4; ++it) {
                const int dd = it*16 + dr;
                float4 v = *reinterpret_cast<const float4*>(X + (size_t)(d0 + dd)*4096 + t0 + tc);
                Xs[dd][tc] = v.x; Xs[dd][tc+1] = v.y; Xs[dd][tc+2] = v.z; Xs[dd][tc+3] = v.w;
            }
        }
        __syncthreads();
        const int tr = tid >> 2, ds = (tid & 3) * 16;
        u32 hb[8], lb[8];
        #pragma unroll
        for (int j = 0; j < 16; j += 2) {
            float a = Xs[ds + j][tr], b = Xs[ds + j + 1][tr];
            u16 ha = f2bf(a), la = f2bf(a - bf2f(ha));
            u16 hbb = f2bf(b), lbb = f2bf(b - bf2f(hbb));
            hb[j >> 1] = (u32)ha | ((u32)hbb << 16);
            lb[j >> 1] = (u32)la | ((u32)lbb << 16);
        }
        u16* orow = XT + (size_t)(t0 + tr)*1024 + d0 + ds;
        uint4 h0; h0.x = hb[0]; h0.y = hb[1]; h0.z = hb[2]; h0.w = hb[3];
        uint4 h1; h1.x = hb[4]; h1.y = hb[5]; h1.z = hb[6]; h1.w = hb[7];
        uint4 l0; l0.x = lb[0]; l0.y = lb[1]; l0.z = lb[2]; l0.w = lb[3];
        uint4 l1; l1.x = lb[4]; l1.y = lb[5]; l1.z = lb[6]; l1.w = lb[7];
        *reinterpret_cast<uint4*>(orow)       = h0;
        *reinterpret_cast<uint4*>(orow + 8)   = h1;
        *reinterpret_cast<uint4*>(orow + 512) = l0;
        *reinterpret_cast<uint4*>(orow + 520) = l1;
        return;
    }
    // ---- per-head setup + W1/CE fold ----
    __shared__ float  Bsh[8*512];      // this head's 8 B-rows (16 KB)
    __shared__ float  Pf[64];
    __shared__ double As[8][8];
    __shared__ double Rs[8][8];
    __shared__ double red[256];
    __shared__ int    sh_s;
    __shared__ float  sh_nrm;
    const int h = blockIdx.x - 512;
    const int i = (tid & 63) >> 3, j = tid & 7;
    const bool act = tid < 64;

    if (act)
        As[i][j] = (double)P[(h*8 + i)*8 + j] - (double)P[(h*8 + j)*8 + i];

    // stage B rows + trace(B B^T)
    const float* Bh = Bmat + h*8*512;
    double ss = 0.0;
    #pragma unroll
    for (int q = 0; q < 16; ++q) {
        float v = Bh[q*256 + tid];
        Bsh[q*256 + tid] = v;
        ss += (double)v * (double)v;
    }
    red[tid] = ss;
    __syncthreads();

    if (tid == 0) {
        double nrm = 0.0;
        for (int r = 0; r < 8; ++r) {
            double rs = 0.0;
            for (int c = 0; c < 8; ++c) rs += fabs(As[r][c]);
            nrm = fmax(nrm, rs);
        }
        int s = 0;
        while (nrm > 0.25 && s < 40) { nrm *= 0.5; ++s; }
        sh_s = s;
        double tr = 0.0;
        for (int q = 0; q < 256; ++q) tr += red[q];
        double ed = exp((double)gamma_log[h]);
        double g  = exp(-ed);
        ws[4096 + h] = (float)g;
        float nf = (float)sqrt((1.0 - g*g) / tr);
        ws[4416 + h] = nf;
        sh_nrm = nf;
    }
    if (tid < 4) ws[4160 + h*4 + tid] = expf(theta_log[h*4 + tid]);
    __syncthreads();

    const int NT = 13;
    if (act) {
        const double sc = ldexp(1.0, -sh_s);
        As[i][j] *= sc;
        Rs[i][j] = (i == j ? 1.0 : 0.0) + As[i][j] / (double)NT;
    }
    __syncthreads();
    for (int k = NT - 1; k >= 1; --k) {
        double t = 0.0;
        if (act) {
            #pragma unroll
            for (int m = 0; m < 8; ++m) t += As[i][m] * Rs[m][j];
        }
        __syncthreads();
        if (act) Rs[i][j] = (i == j ? 1.0 : 0.0) + t / (double)k;
        __syncthreads();
    }
    const int nsq = sh_s;
    for (int q = 0; q < nsq; ++q) {
        double t = 0.0;
        if (act) {
            #pragma unroll
            for (int m = 0; m < 8; ++m) t += Rs[i][m] * Rs[m][j];
        }
        __syncthreads();
        if (act) Rs[i][j] = t;
        __syncthreads();
    }
    if (act) Pf[i*8 + j] = (float)Rs[i][j];
    __syncthreads();

    const float nrmf = sh_nrm;
    // ---- W1 rows k = 8h+N:  W1[k][d] = nrm * sum_n Pm[N][n] * B[n][d] ----
    {
        const int d0 = 2*tid;
        #pragma unroll
        for (int N = 0; N < 8; ++N) {
            float a0 = 0.f, a1 = 0.f;
            #pragma unroll
            for (int n = 0; n < 8; ++n) {
                const float pm = Pf[N*8 + n];
                a0 += pm * Bsh[n*512 + d0];
                a1 += pm * Bsh[n*512 + d0 + 1];
            }
            a0 *= nrmf; a1 *= nrmf;
            u16 h0 = f2bf(a0), h1 = f2bf(a1);
            u16 l0 = f2bf_trunc(a0 - bf2f(h0)), l1 = f2bf_trunc(a1 - bf2f(h1));
            u16* base = W1pk + (size_t)(8*h + N)*1024;
            *reinterpret_cast<u32*>(base + d0)       = (u32)h0 | ((u32)h1 << 16);
            *reinterpret_cast<u32*>(base + 512 + d0) = (u32)l0 | ((u32)l1 << 16);
        }
    }
    // ---- CE column-slice: CE[e][8h+N] = sum_n Pm[N][n] * C[e][8h+n] ----
    #pragma unroll
    for (int ee = 0; ee < 2; ++ee) {
        const int e = ee*256 + tid;
        float4 c0 = *reinterpret_cast<const float4*>(C + (size_t)e*512 + 8*h);
        float4 c1 = *reinterpret_cast<const float4*>(C + (size_t)e*512 + 8*h + 4);
        float cv[8] = {c0.x, c0.y, c0.z, c0.w, c1.x, c1.y, c1.z, c1.w};
        u16 hv[8], lv[8];
        #pragma unroll
        for (int N = 0; N < 8; ++N) {
            float acc = 0.f;
            #pragma unroll
            for (int n = 0; n < 8; ++n) acc += Pf[N*8 + n] * cv[n];
            hv[N] = f2bf(acc);
            lv[N] = f2bf_trunc(acc - bf2f(hv[N]));
        }
        u16* base = CEpk + (size_t)e*1024 + 8*h;
        uint4 wh; wh.x = (u32)hv[0] | ((u32)hv[1] << 16); wh.y = (u32)hv[2] | ((u32)hv[3] << 16);
                  wh.z = (u32)hv[4] | ((u32)hv[5] << 16); wh.w = (u32)hv[6] | ((u32)hv[7] << 16);
        uint4 wl; wl.x = (u32)lv[0] | ((u32)lv[1] << 16); wl.y = (u32)lv[2] | ((u32)lv[3] << 16);
                  wl.z = (u32)lv[4] | ((u32)lv[5] << 16); wl.w = (u32)lv[6] | ((u32)lv[7] << 16);
        *reinterpret_cast<uint4*>(base)       = wh;
        *reinterpret_cast<uint4*>(base + 512) = wl;
    }
}

// ---------------------------------------------------------------------------
// Kernel 2/4: split-bf16 MFMA GEMM, 64x64 tile, 4 waves 2x2, BK=64, LDS dbuf.
// (R6-proven staging: XTpk packed rows, conflict-free b128 LDS writes.)
// MODE 0: A = XTpk; epilogue = in-LDS local scan -> U + E.
// MODE 1: A = U f32 + carry fixup during staging; epilogue = +D*x -> out.
#define MFMA_BF16(A_, B_, C_) __builtin_amdgcn_mfma_f32_16x16x32_bf16(A_, B_, C_, 0, 0, 0)
template<int MODE>
__global__ __launch_bounds__(256, 2) void k_gemm(const u16* __restrict__ Apk,
                                                 const float* __restrict__ Af,
                                                 const u16* __restrict__ Bpk,
                                                 float* __restrict__ Cout,
                                                 const u16* __restrict__ XT,
                                                 const float* __restrict__ Dvec,
                                                 const float* __restrict__ wsro,
                                                 float* __restrict__ E,
                                                 const float* __restrict__ S,
                                                 const float* __restrict__ TAB) {
    __shared__ char smem[73728];              // 2 x (Ah,Al,Bh,Bl of 9216 B)
    float* Ut = (float*)smem;                 // MODE0 epilogue scratch (18432 B)

    const int tid = threadIdx.x;
    const int bid = blockIdx.x;
    const int tile = (bid & 7) * 64 + (bid >> 3);   // XCD-chunked swizzle
    const int mt = tile >> 3, nt = tile & 7;
    const int m0 = mt * 64, n0 = nt * 64;
    const int lane = tid & 63, wid = tid >> 6;
    const int wm = wid >> 1, wn = wid & 1;
    const int lr = lane & 15, lc = lane >> 4;
    const int sr = tid >> 2, ss = (tid & 3) * 16;   // staging: row, 16-elem seg

    f32x4 acc00 = {0.f,0.f,0.f,0.f}, acc01 = acc00, acc10 = acc00, acc11 = acc00;

    const int tA = m0 + sr;                 // staging row (t index)
    const int cA = tA >> 4, iA = tA & 15;   // chunk, offset (MODE1 fix)
    const u16* Brow = Bpk + (size_t)(n0 + sr)*1024 + ss;
    const u16* Arow = (MODE == 0) ? (Apk + (size_t)tA*1024 + ss) : (const u16*)0;
    const float* Urow = (MODE == 1) ? (Af + (size_t)tA*512 + ss) : (const float*)0;

    float4 rb0, rb1, rb2, rb3;              // B prefetch regs
    float4 ra0, ra1, ra2, ra3;              // MODE0 A prefetch
    float4 ru[4], rtb[4], rsv[4];           // MODE1 A prefetch

    auto LOADREGS = [&](int k0) {
        rb0 = *reinterpret_cast<const float4*>(Brow + k0);
        rb1 = *reinterpret_cast<const float4*>(Brow + k0 + 8);
        rb2 = *reinterpret_cast<const float4*>(Brow + 512 + k0);
        rb3 = *reinterpret_cast<const float4*>(Brow + 512 + k0 + 8);
        if constexpr (MODE == 0) {
            ra0 = *reinterpret_cast<const float4*>(Arow + k0);
            ra1 = *reinterpret_cast<const float4*>(Arow + k0 + 8);
            ra2 = *reinterpret_cast<const float4*>(Arow + 512 + k0);
            ra3 = *reinterpret_cast<const float4*>(Arow + 512 + k0 + 8);
        } else {
            const int p0 = (k0 + ss) >> 1;
            #pragma unroll
            for (int j = 0; j < 4; ++j) {
                ru[j]  = *reinterpret_cast<const float4*>(Urow + k0 + 4*j);
                rtb[j] = *reinterpret_cast<const float4*>(TAB + ((size_t)iA*256 + p0 + 2*j)*2);
                rsv[j] = *reinterpret_cast<const float4*>(S + (size_t)cA*512 + 2*p0 + 4*j);
            }
        }
    };
    auto STORE = [&](u16* Ah, u16* Al, u16* Bh, u16* Bl) {
        if constexpr (MODE == 0) {
            *reinterpret_cast<float4*>(&Ah[sr*72 + ss])     = ra0;
            *reinterpret_cast<float4*>(&Ah[sr*72 + ss + 8]) = ra1;
            *reinterpret_cast<float4*>(&Al[sr*72 + ss])     = ra2;
            *reinterpret_cast<float4*>(&Al[sr*72 + ss + 8]) = ra3;
        } else {
            #pragma unroll
            for (int j = 0; j < 4; ++j) {
                float4 u = ru[j], tb = rtb[j], sv = rsv[j];
                u.x += tb.x*sv.x - tb.y*sv.y;
                u.y += tb.y*sv.x + tb.x*sv.y;
                u.z += tb.z*sv.z - tb.w*sv.w;
                u.w += tb.w*sv.z + tb.z*sv.w;
                u16 hx = f2bf(u.x), hy = f2bf(u.y), hz = f2bf(u.z), hw = f2bf(u.w);
                u16 lx = f2bf_trunc(u.x - bf2f(hx)), ly = f2bf_trunc(u.y - bf2f(hy));
                u16 lz = f2bf_trunc(u.z - bf2f(hz)), lw = f2bf_trunc(u.w - bf2f(hw));
                uint2 wh; wh.x = (u32)hx | ((u32)hy << 16); wh.y = (u32)hz | ((u32)hw << 16);
                uint2 wl; wl.x = (u32)lx | ((u32)ly << 16); wl.y = (u32)lz | ((u32)lw << 16);
                *reinterpret_cast<uint2*>(&Ah[sr*72 + ss + 4*j]) = wh;
                *reinterpret_cast<uint2*>(&Al[sr*72 + ss + 4*j]) = wl;
            }
        }
        *reinterpret_cast<float4*>(&Bh[sr*72 + ss])     = rb0;
        *reinterpret_cast<float4*>(&Bh[sr*72 + ss + 8]) = rb1;
        *reinterpret_cast<float4*>(&Bl[sr*72 + ss])     = rb2;
        *reinterpret_cast<float4*>(&Bl[sr*72 + ss + 8]) = rb3;
    };
    auto MFMAS = [&](const u16* Ah, const u16* Al, const u16* Bh, const u16* Bl) {
        #pragma unroll
        for (int kk = 0; kk < 2; ++kk) {
            const int ko = kk*32 + lc*8;
            const int ra0i = (wm*32 + lr)*72 + ko,  ra1i = ra0i + 16*72;
            const int rb0i = (wn*32 + lr)*72 + ko,  rb1i = rb0i + 16*72;
            bf16x8 fah0 = *reinterpret_cast<const bf16x8*>(&Ah[ra0i]);
            bf16x8 fah1 = *reinterpret_cast<const bf16x8*>(&Ah[ra1i]);
            bf16x8 fal0 = *reinterpret_cast<const bf16x8*>(&Al[ra0i]);
            bf16x8 fal1 = *reinterpret_cast<const bf16x8*>(&Al[ra1i]);
            bf16x8 fbh0 = *reinterpret_cast<const bf16x8*>(&Bh[rb0i]);
            bf16x8 fbh1 = *reinterpret_cast<const bf16x8*>(&Bh[rb1i]);
            bf16x8 fbl0 = *reinterpret_cast<const bf16x8*>(&Bl[rb0i]);
            bf16x8 fbl1 = *reinterpret_cast<const bf16x8*>(&Bl[rb1i]);
            acc00 = MFMA_BF16(fah0, fbl0, acc00);
            acc00 = MFMA_BF16(fal0, fbh0, acc00);
            acc00 = MFMA_BF16(fah0, fbh0, acc00);
            acc01 = MFMA_BF16(fah0, fbl1, acc01);
            acc01 = MFMA_BF16(fal0, fbh1, acc01);
            acc01 = MFMA_BF16(fah0, fbh1, acc01);
            acc10 = MFMA_BF16(fah1, fbl0, acc10);
            acc10 = MFMA_BF16(fal1, fbh0, acc10);
            acc10 = MFMA_BF16(fah1, fbh0, acc10);
            acc11 = MFMA_BF16(fah1, fbl1, acc11);
            acc11 = MFMA_BF16(fal1, fbh1, acc11);
            acc11 = MFMA_BF16(fah1, fbh1, acc11);
        }
    };

    u16* buf0 = (u16*)smem;
    u16* buf1 = (u16*)(smem + 36864);

    LOADREGS(0);
    STORE(buf0, buf0 + 4608, buf0 + 9216, buf0 + 13824);
    __syncthreads();

    #pragma unroll
    for (int s = 0; s < 8; ++s) {
        u16* bp = (s & 1) ? buf1 : buf0;
        u16* bq = (s & 1) ? buf0 : buf1;
        if (s < 7) LOADREGS((s + 1) * 64);
        MFMAS(bp, bp + 4608, bp + 9216, bp + 13824);
        if (s < 7) STORE(bq, bq + 4608, bq + 9216, bq + 13824);
        __syncthreads();
    }

    if constexpr (MODE == 0) {
        // ---- fused local scan epilogue ----
        #pragma unroll
        for (int im = 0; im < 2; ++im) {
            #pragma unroll
            for (int in = 0; in < 2; ++in) {
                f32x4 v = (im == 0) ? (in == 0 ? acc00 : acc01)
                                    : (in == 0 ? acc10 : acc11);
                const int row0 = wm*32 + im*16 + lc*4;
                const int col  = wn*32 + in*16 + lr;
                #pragma unroll
                for (int rg = 0; rg < 4; ++rg)
                    Ut[(row0 + rg)*72 + col] = v[rg];
            }
        }
        __syncthreads();
        if (tid < 128) {
            const int cc = tid >> 5, pp = tid & 31;   // local chunk 0..3, local pair
            const int pg = nt*32 + pp;                // global pair
            const float th = wsro[4160 + pg];
            const float g  = wsro[4096 + (pg >> 2)];
            const float cs = cosf(th), sn = sinf(th);
            float h0 = 0.f, h1 = 0.f;
            float* col = Ut + (cc*16)*72 + 2*pp;
            #pragma unroll
            for (int i = 0; i < CHUNK; ++i) {
                float a = col[i*72], b = col[i*72 + 1];
                float n0v = g*(cs*h0 - sn*h1) + a;
                float n1v = g*(sn*h0 + cs*h1) + b;
                col[i*72] = n0v; col[i*72 + 1] = n1v;
                h0 = n0v; h1 = n1v;
            }
            E[(size_t)(mt*4 + cc)*512 + 2*pg]     = h0;
            E[(size_t)(mt*4 + cc)*512 + 2*pg + 1] = h1;
        }
        __syncthreads();
        const int row = tid >> 2, cseg = (tid & 3) * 16;
        #pragma unroll
        for (int j = 0; j < 4; ++j) {
            float4 v = *reinterpret_cast<const float4*>(&Ut[row*72 + cseg + 4*j]);
            *reinterpret_cast<float4*>(Cout + (size_t)(m0 + row)*512 + n0 + cseg + 4*j) = v;
        }
    } else {
        // ---- D*x epilogue ----
        #pragma unroll
        for (int im = 0; im < 2; ++im) {
            #pragma unroll
            for (int in = 0; in < 2; ++in) {
                f32x4 v = (im == 0) ? (in == 0 ? acc00 : acc01)
                                    : (in == 0 ? acc10 : acc11);
                const int row0 = m0 + wm*32 + im*16 + lc*4;
                const int col  = n0 + wn*32 + in*16 + lr;
                const float dv = Dvec[col];
                #pragma unroll
                for (int rg = 0; rg < 4; ++rg) {
                    const int t = row0 + rg;
                    float xv = bf2f(XT[(size_t)t*1024 + col]) + bf2f(XT[(size_t)t*1024 + 512 + col]);
                    Cout[(size_t)t*512 + col] = v[rg] + dv*xv;
                }
            }
        }
    }
}

// ---------------------------------------------------------------------------
// Kernel 3: wave-parallel carry. One wave per pair p; lane l owns chunks
// 4l..4l+3. Chunk-step operator L = gamma^16 R(16*theta); scan multipliers
// L^{4*2^d} computed in closed form (fp64). Also emits TAB in closed form.
__global__ void k_carry(const float* __restrict__ E, float* __restrict__ S,
                        float* __restrict__ TAB,
                        const float* __restrict__ theta_log,
                        const float* __restrict__ gamma_log) {
    const int w = threadIdx.x >> 6, l = threadIdx.x & 63;
    const int p = blockIdx.x*4 + w;
    const double th = exp((double)theta_log[p]);
    const double ed = exp((double)gamma_log[p >> 2]);

    if (l < CHUNK) {   // TAB[i] = gamma^{i+1} * (cos,sin)((i+1)theta)
        double a = (double)(l + 1) * th;
        double g = exp(-(double)(l + 1) * ed);
        TAB[((size_t)l*256 + p)*2 + 0] = (float)(g * cos(a));
        TAB[((size_t)l*256 + p)*2 + 1] = (float)(g * sin(a));
    }

    const double a16 = 16.0*th, g16 = exp(-16.0*ed);
    const float Lc = (float)(g16*cos(a16)), Ls = (float)(g16*sin(a16));

    const float* Ep = E + 2*p;
    float2 e0 = *reinterpret_cast<const float2*>(Ep + (size_t)(4*l + 0)*512);
    float2 e1 = *reinterpret_cast<const float2*>(Ep + (size_t)(4*l + 1)*512);
    float2 e2 = *reinterpret_cast<const float2*>(Ep + (size_t)(4*l + 2)*512);
    float2 e3 = *reinterpret_cast<const float2*>(Ep + (size_t)(4*l + 3)*512);

    float2 v = e0;
    v = make_float2(Lc*v.x - Ls*v.y + e1.x, Ls*v.x + Lc*v.y + e1.y);
    v = make_float2(Lc*v.x - Ls*v.y + e2.x, Ls*v.x + Lc*v.y + e2.y);
    v = make_float2(Lc*v.x - Ls*v.y + e3.x, Ls*v.x + Lc*v.y + e3.y);

    #pragma unroll
    for (int d = 0; d < 6; ++d) {
        const int sh = 1 << d;
        const double aa = 64.0 * (double)sh * th;
        const double gg = exp(-64.0 * (double)sh * ed);
        const float Mc = (float)(gg*cos(aa)), Ms = (float)(gg*sin(aa));
        float px = __shfl_up(v.x, sh, 64);
        float py = __shfl_up(v.y, sh, 64);
        if (l >= sh) {
            v.x += Mc*px - Ms*py;
            v.y += Ms*px + Mc*py;
        }
    }

    float sx = __shfl_up(v.x, 1, 64), sy = __shfl_up(v.y, 1, 64);
    float2 s = (l == 0) ? make_float2(0.f, 0.f) : make_float2(sx, sy);
    float* Sp = S + 2*p;
    *reinterpret_cast<float2*>(Sp + (size_t)(4*l + 0)*512) = s;
    s = make_float2(Lc*s.x - Ls*s.y + e0.x, Ls*s.x + Lc*s.y + e0.y);
    *reinterpret_cast<float2*>(Sp + (size_t)(4*l + 1)*512) = s;
    s = make_float2(Lc*s.x - Ls*s.y + e1.x, Ls*s.x + Lc*s.y + e1.y);
    *reinterpret_cast<float2*>(Sp + (size_t)(4*l + 2)*512) = s;
    s = make_float2(Lc*s.x - Ls*s.y + e2.x, Ls*s.x + Lc*s.y + e2.y);
    *reinterpret_cast<float2*>(Sp + (size_t)(4*l + 3)*512) = s;
}

// ---------------------------------------------------------------------------
extern "C" void kernel_launch(void* const* d_in, const int* in_sizes, int n_in,
                              void* d_out, int out_size, void* d_ws, size_t ws_size,
                              hipStream_t stream) {
    const float* X  = (const float*)d_in[0];  // (8,1,512,1,4096); batch 0 = first 2M floats
    const float* th = (const float*)d_in[1];
    const float* P  = (const float*)d_in[2];
    const float* Bm = (const float*)d_in[3];
    const float* C  = (const float*)d_in[4];
    const float* Dv = (const float*)d_in[5];
    const float* gl = (const float*)d_in[6];
    char* wsb = (char*)d_ws;
    float* ws   = (float*)wsb;
    u16*   W1pk = (u16*)(wsb + 32768);
    u16*   CEpk = (u16*)(wsb + 1081344);
    u16*   XTpk = (u16*)(wsb + 2129920);
    float* U    = (float*)(wsb + 10518528);
    float* E    = (float*)(wsb + 18907136);
    float* S    = (float*)(wsb + 19431424);
    float* TAB  = (float*)(wsb + 19955712);
    float* out  = (float*)d_out;

    k_pre<<<576, 256, 0, stream>>>(X, XTpk, P, Bm, C, th, gl, ws, W1pk, CEpk);
    k_gemm<0><<<512, 256, 0, stream>>>(XTpk, (const float*)0, W1pk, U, XTpk, Dv, ws, E, S, TAB);
    k_carry<<<64, 256, 0, stream>>>(E, S, TAB, th, gl);
    k_gemm<1><<<512, 256, 0, stream>>>((const u16*)0, U, CEpk, out, XTpk, Dv, ws, E, S, TAB);
}

// Round 9
// 147.322 us; speedup vs baseline: 1.0484x; 1.0353x over previous
//
#include <hip/hip_runtime.h>
#include <math.h>

// Problem constants
#define NHEADS   64
#define TLEN     4096
#define CHUNK    16
#define NCHUNK   256  // TLEN / CHUNK

typedef unsigned short u16;
typedef unsigned int   u32;
typedef __attribute__((ext_vector_type(8))) short bf16x8;   // 8 bf16 in 4 VGPRs
typedef __attribute__((ext_vector_type(4))) float f32x4;

__device__ __forceinline__ u16 f2bf(float x) {               // RNE f32->bf16
    u32 u = __float_as_uint(x);
    u32 r = (u + 0x7FFFu + ((u >> 16) & 1u)) >> 16;
    return (u16)r;
}
__device__ __forceinline__ float bf2f(u16 h) { return __uint_as_float(((u32)h) << 16); }
__device__ __forceinline__ u16 f2bf_trunc(float x) { return (u16)(__float_as_uint(x) >> 16); }

// ws layout (BYTE offsets)
//  params f32 : 0        (gamma @4096, theta @4160, norm @4416)
//  W1pk  u16  : 32768    512 rows x (512 hi + 512 lo)          (1 MB)
//  CEpk  u16  : 1081344  512 rows x (512 hi + 512 lo)          (1 MB)
//  XTpk  u16  : 2129920  4096 rows x (512 hi + 512 lo)         (8 MB)
//  U     f32  : 10518528 4096 x 512 (scanned local states)     (8 MB)
//  E     f32  : 18907136 256 x 512                             (512 KB)
//  S     f32  : 19431424 256 x 512                             (512 KB)
//  TAB   f32  : 19955712 16 x 256 x 2                          (32 KB)

// ---------------------------------------------------------------------------
// Kernel 1 (merged): blocks 0..511 transpose+pack X; blocks 512..575 do
// per-head setup (expm via fp64 scaling-and-squaring Taylor).
__global__ void k_pre(const float* __restrict__ X, u16* __restrict__ XT,
                      const float* __restrict__ P,
                      const float* __restrict__ Bmat,
                      const float* __restrict__ theta_log,
                      const float* __restrict__ gamma_log,
                      float* __restrict__ ws) {
    const int tid = threadIdx.x;
    if (blockIdx.x < 512) {
        // ---- X[d][t] -> XTpk[t]{hi[512],lo[512]} ----
        __shared__ float Xs[64][65];
        const int t0 = (blockIdx.x & 63) * 64, d0 = (blockIdx.x >> 6) * 64;
        {
            const int dr = tid >> 4, tc = (tid & 15) * 4;
            #pragma unroll
            for (int it = 0; it < 4; ++it) {
                const int dd = it*16 + dr;
                float4 v = *reinterpret_cast<const float4*>(X + (size_t)(d0 + dd)*4096 + t0 + tc);
                Xs[dd][tc] = v.x; Xs[dd][tc+1] = v.y; Xs[dd][tc+2] = v.z; Xs[dd][tc+3] = v.w;
            }
        }
        __syncthreads();
        const int tr = tid >> 2, ds = (tid & 3) * 16;
        u32 hb[8], lb[8];
        #pragma unroll
        for (int j = 0; j < 16; j += 2) {
            float a = Xs[ds + j][tr], b = Xs[ds + j + 1][tr];
            u16 ha = f2bf(a), la = f2bf(a - bf2f(ha));
            u16 hbb = f2bf(b), lbb = f2bf(b - bf2f(hbb));
            hb[j >> 1] = (u32)ha | ((u32)hbb << 16);
            lb[j >> 1] = (u32)la | ((u32)lbb << 16);
        }
        u16* orow = XT + (size_t)(t0 + tr)*1024 + d0 + ds;
        uint4 h0; h0.x = hb[0]; h0.y = hb[1]; h0.z = hb[2]; h0.w = hb[3];
        uint4 h1; h1.x = hb[4]; h1.y = hb[5]; h1.z = hb[6]; h1.w = hb[7];
        uint4 l0; l0.x = lb[0]; l0.y = lb[1]; l0.z = lb[2]; l0.w = lb[3];
        uint4 l1; l1.x = lb[4]; l1.y = lb[5]; l1.z = lb[6]; l1.w = lb[7];
        *reinterpret_cast<uint4*>(orow)       = h0;
        *reinterpret_cast<uint4*>(orow + 8)   = h1;
        *reinterpret_cast<uint4*>(orow + 512) = l0;
        *reinterpret_cast<uint4*>(orow + 520) = l1;
        return;
    }
    // ---- per-head setup ----
    __shared__ double As[8][8];
    __shared__ double Rs[8][8];
    __shared__ double red[256];
    __shared__ int sh_s;
    const int h = blockIdx.x - 512;
    const int i = (tid & 63) >> 3, j = tid & 7;
    const bool act = tid < 64;

    if (act)
        As[i][j] = (double)P[(h*8 + i)*8 + j] - (double)P[(h*8 + j)*8 + i];

    const float* Bh = Bmat + h*8*512;
    double ss = 0.0;
    #pragma unroll
    for (int q = 0; q < 16; ++q) { float v = Bh[q*256 + tid]; ss += (double)v * (double)v; }
    red[tid] = ss;
    __syncthreads();

    if (tid == 0) {
        double nrm = 0.0;
        for (int r = 0; r < 8; ++r) {
            double rs = 0.0;
            for (int c = 0; c < 8; ++c) rs += fabs(As[r][c]);
            nrm = fmax(nrm, rs);
        }
        int s = 0;
        while (nrm > 0.25 && s < 40) { nrm *= 0.5; ++s; }
        sh_s = s;
        double tr = 0.0;
        for (int q = 0; q < 256; ++q) tr += red[q];
        double ed = exp((double)gamma_log[h]);
        double g  = exp(-ed);
        ws[4096 + h] = (float)g;
        ws[4416 + h] = (float)sqrt((1.0 - g*g) / tr);
    }
    if (tid < 4) ws[4160 + h*4 + tid] = expf(theta_log[h*4 + tid]);
    __syncthreads();

    const int NT = 13;
    if (act) {
        const double sc = ldexp(1.0, -sh_s);
        As[i][j] *= sc;
        Rs[i][j] = (i == j ? 1.0 : 0.0) + As[i][j] / (double)NT;
    }
    __syncthreads();
    for (int k = NT - 1; k >= 1; --k) {
        double t = 0.0;
        if (act) {
            #pragma unroll
            for (int m = 0; m < 8; ++m) t += As[i][m] * Rs[m][j];
        }
        __syncthreads();
        if (act) Rs[i][j] = (i == j ? 1.0 : 0.0) + t / (double)k;
        __syncthreads();
    }
    const int nsq = sh_s;
    for (int q = 0; q < nsq; ++q) {
        double t = 0.0;
        if (act) {
            #pragma unroll
            for (int m = 0; m < 8; ++m) t += Rs[i][m] * Rs[m][j];
        }
        __syncthreads();
        if (act) Rs[i][j] = t;
        __syncthreads();
    }
    if (act) ws[h*64 + i*8 + j] = (float)Rs[i][j];
}

// ---------------------------------------------------------------------------
// Kernel 2: fold Pm into B (-> W1pk[k][d]) and C (-> CEpk[e][k]), pack hi/lo bf16.
__global__ void k_proj(const float* __restrict__ Bmat,
                       const float* __restrict__ C,
                       const float* __restrict__ ws_ro,
                       u16* __restrict__ W1pk,
                       u16* __restrict__ CEpk) {
    const int gid = blockIdx.x * 256 + threadIdx.x;
    if (gid < 512*512) {
        const int k = gid >> 9, d = gid & 511;
        const int h = k >> 3, N = k & 7;
        const float* Pm = ws_ro + h*64 + N*8;
        const float nrm = ws_ro[4416 + h];
        float acc = 0.f;
        #pragma unroll
        for (int n = 0; n < 8; ++n) acc += Pm[n] * Bmat[(h*8 + n)*512 + d];
        acc *= nrm;
        u16 hi = f2bf(acc), lo = f2bf(acc - bf2f(hi));
        W1pk[k*1024 + d] = hi;
        W1pk[k*1024 + 512 + d] = lo;
    } else {
        const int g2 = gid - 512*512;
        const int e = g2 >> 9, k = g2 & 511;
        const int h = k >> 3, N = k & 7;
        const float* Pm = ws_ro + h*64 + N*8;
        float acc = 0.f;
        #pragma unroll
        for (int n = 0; n < 8; ++n) acc += Pm[n] * C[e*512 + h*8 + n];
        u16 hi = f2bf(acc), lo = f2bf(acc - bf2f(hi));
        CEpk[e*1024 + k] = hi;
        CEpk[e*1024 + 512 + k] = lo;
    }
}

// ---------------------------------------------------------------------------
// Kernel 3/5: split-bf16 MFMA GEMM, 64x64 tile, 4 waves 2x2, BK=64.
// DOUBLE-BUFFERED LDS: one barrier per k-step; reg prefetch of step s+1
// issued before step s's MFMA; stores for s+1 land after, into the other buf.
// MODE 0: A = XTpk; epilogue = in-LDS local scan -> U + E.
// MODE 1: A = U f32 + carry fixup during staging; epilogue = +D*x -> out.
#define MFMA_BF16(A_, B_, C_) __builtin_amdgcn_mfma_f32_16x16x32_bf16(A_, B_, C_, 0, 0, 0)
template<int MODE>
__global__ __launch_bounds__(256, 2) void k_gemm(const u16* __restrict__ Apk,
                                                 const float* __restrict__ Af,
                                                 const u16* __restrict__ Bpk,
                                                 float* __restrict__ Cout,
                                                 const u16* __restrict__ XT,
                                                 const float* __restrict__ Dvec,
                                                 const float* __restrict__ wsro,
                                                 float* __restrict__ E,
                                                 const float* __restrict__ S,
                                                 const float* __restrict__ TAB) {
    __shared__ char smem[73728];              // 2 x (Ah,Al,Bh,Bl of 9216 B)
    float* Ut = (float*)smem;                 // MODE0 epilogue scratch (18432 B)

    const int tid = threadIdx.x;
    const int bid = blockIdx.x;
    const int tile = (bid & 7) * 64 + (bid >> 3);   // XCD-chunked swizzle
    const int mt = tile >> 3, nt = tile & 7;
    const int m0 = mt * 64, n0 = nt * 64;
    const int lane = tid & 63, wid = tid >> 6;
    const int wm = wid >> 1, wn = wid & 1;
    const int lr = lane & 15, lc = lane >> 4;
    const int sr = tid >> 2, ss = (tid & 3) * 16;   // staging: row, 16-elem seg

    f32x4 acc00 = {0.f,0.f,0.f,0.f}, acc01 = acc00, acc10 = acc00, acc11 = acc00;

    const int tA = m0 + sr;                 // staging row (t index)
    const int cA = tA >> 4, iA = tA & 15;   // chunk, offset (MODE1 fix)
    const u16* Brow = Bpk + (size_t)(n0 + sr)*1024 + ss;
    const u16* Arow = (MODE == 0) ? (Apk + (size_t)tA*1024 + ss) : (const u16*)0;
    const float* Urow = (MODE == 1) ? (Af + (size_t)tA*512 + ss) : (const float*)0;

    float4 rb0, rb1, rb2, rb3;              // B prefetch regs
    float4 ra0, ra1, ra2, ra3;              // MODE0 A prefetch
    float4 ru[4], rtb[4], rsv[4];           // MODE1 A prefetch

    auto LOADREGS = [&](int k0) {
        rb0 = *reinterpret_cast<const float4*>(Brow + k0);
        rb1 = *reinterpret_cast<const float4*>(Brow + k0 + 8);
        rb2 = *reinterpret_cast<const float4*>(Brow + 512 + k0);
        rb3 = *reinterpret_cast<const float4*>(Brow + 512 + k0 + 8);
        if constexpr (MODE == 0) {
            ra0 = *reinterpret_cast<const float4*>(Arow + k0);
            ra1 = *reinterpret_cast<const float4*>(Arow + k0 + 8);
            ra2 = *reinterpret_cast<const float4*>(Arow + 512 + k0);
            ra3 = *reinterpret_cast<const float4*>(Arow + 512 + k0 + 8);
        } else {
            const int p0 = (k0 + ss) >> 1;
            #pragma unroll
            for (int j = 0; j < 4; ++j) {
                ru[j]  = *reinterpret_cast<const float4*>(Urow + k0 + 4*j);
                rtb[j] = *reinterpret_cast<const float4*>(TAB + ((size_t)iA*256 + p0 + 2*j)*2);
                rsv[j] = *reinterpret_cast<const float4*>(S + (size_t)cA*512 + 2*p0 + 4*j);
            }
        }
    };
    auto STORE = [&](u16* Ah, u16* Al, u16* Bh, u16* Bl) {
        if constexpr (MODE == 0) {
            *reinterpret_cast<float4*>(&Ah[sr*72 + ss])     = ra0;
            *reinterpret_cast<float4*>(&Ah[sr*72 + ss + 8]) = ra1;
            *reinterpret_cast<float4*>(&Al[sr*72 + ss])     = ra2;
            *reinterpret_cast<float4*>(&Al[sr*72 + ss + 8]) = ra3;
        } else {
            #pragma unroll
            for (int j = 0; j < 4; ++j) {
                float4 u = ru[j], tb = rtb[j], sv = rsv[j];
                u.x += tb.x*sv.x - tb.y*sv.y;
                u.y += tb.y*sv.x + tb.x*sv.y;
                u.z += tb.z*sv.z - tb.w*sv.w;
                u.w += tb.w*sv.z + tb.z*sv.w;
                u16 hx = f2bf(u.x), hy = f2bf(u.y), hz = f2bf(u.z), hw = f2bf(u.w);
                u16 lx = f2bf_trunc(u.x - bf2f(hx)), ly = f2bf_trunc(u.y - bf2f(hy));
                u16 lz = f2bf_trunc(u.z - bf2f(hz)), lw = f2bf_trunc(u.w - bf2f(hw));
                uint2 wh; wh.x = (u32)hx | ((u32)hy << 16); wh.y = (u32)hz | ((u32)hw << 16);
                uint2 wl; wl.x = (u32)lx | ((u32)ly << 16); wl.y = (u32)lz | ((u32)lw << 16);
                *reinterpret_cast<uint2*>(&Ah[sr*72 + ss + 4*j]) = wh;
                *reinterpret_cast<uint2*>(&Al[sr*72 + ss + 4*j]) = wl;
            }
        }
        *reinterpret_cast<float4*>(&Bh[sr*72 + ss])     = rb0;
        *reinterpret_cast<float4*>(&Bh[sr*72 + ss + 8]) = rb1;
        *reinterpret_cast<float4*>(&Bl[sr*72 + ss])     = rb2;
        *reinterpret_cast<float4*>(&Bl[sr*72 + ss + 8]) = rb3;
    };
    auto MFMAS = [&](const u16* Ah, const u16* Al, const u16* Bh, const u16* Bl) {
        #pragma unroll
        for (int kk = 0; kk < 2; ++kk) {
            const int ko = kk*32 + lc*8;
            const int ra0i = (wm*32 + lr)*72 + ko,  ra1i = ra0i + 16*72;
            const int rb0i = (wn*32 + lr)*72 + ko,  rb1i = rb0i + 16*72;
            bf16x8 fah0 = *reinterpret_cast<const bf16x8*>(&Ah[ra0i]);
            bf16x8 fah1 = *reinterpret_cast<const bf16x8*>(&Ah[ra1i]);
            bf16x8 fal0 = *reinterpret_cast<const bf16x8*>(&Al[ra0i]);
            bf16x8 fal1 = *reinterpret_cast<const bf16x8*>(&Al[ra1i]);
            bf16x8 fbh0 = *reinterpret_cast<const bf16x8*>(&Bh[rb0i]);
            bf16x8 fbh1 = *reinterpret_cast<const bf16x8*>(&Bh[rb1i]);
            bf16x8 fbl0 = *reinterpret_cast<const bf16x8*>(&Bl[rb0i]);
            bf16x8 fbl1 = *reinterpret_cast<const bf16x8*>(&Bl[rb1i]);
            acc00 = MFMA_BF16(fah0, fbl0, acc00);
            acc00 = MFMA_BF16(fal0, fbh0, acc00);
            acc00 = MFMA_BF16(fah0, fbh0, acc00);
            acc01 = MFMA_BF16(fah0, fbl1, acc01);
            acc01 = MFMA_BF16(fal0, fbh1, acc01);
            acc01 = MFMA_BF16(fah0, fbh1, acc01);
            acc10 = MFMA_BF16(fah1, fbl0, acc10);
            acc10 = MFMA_BF16(fal1, fbh0, acc10);
            acc10 = MFMA_BF16(fah1, fbh0, acc10);
            acc11 = MFMA_BF16(fah1, fbl1, acc11);
            acc11 = MFMA_BF16(fal1, fbh1, acc11);
            acc11 = MFMA_BF16(fah1, fbh1, acc11);
        }
    };

    u16* buf0 = (u16*)smem;
    u16* buf1 = (u16*)(smem + 36864);

    LOADREGS(0);
    STORE(buf0, buf0 + 4608, buf0 + 9216, buf0 + 13824);
    __syncthreads();

    #pragma unroll
    for (int s = 0; s < 8; ++s) {
        u16* bp = (s & 1) ? buf1 : buf0;
        u16* bq = (s & 1) ? buf0 : buf1;
        if (s < 7) LOADREGS((s + 1) * 64);
        MFMAS(bp, bp + 4608, bp + 9216, bp + 13824);
        if (s < 7) STORE(bq, bq + 4608, bq + 9216, bq + 13824);
        __syncthreads();
    }

    if constexpr (MODE == 0) {
        // ---- fused local scan epilogue ----
        #pragma unroll
        for (int im = 0; im < 2; ++im) {
            #pragma unroll
            for (int in = 0; in < 2; ++in) {
                f32x4 v = (im == 0) ? (in == 0 ? acc00 : acc01)
                                    : (in == 0 ? acc10 : acc11);
                const int row0 = wm*32 + im*16 + lc*4;
                const int col  = wn*32 + in*16 + lr;
                #pragma unroll
                for (int rg = 0; rg < 4; ++rg)
                    Ut[(row0 + rg)*72 + col] = v[rg];
            }
        }
        __syncthreads();
        if (tid < 128) {
            const int cc = tid >> 5, pp = tid & 31;   // local chunk 0..3, local pair
            const int pg = nt*32 + pp;                // global pair
            const float th = wsro[4160 + pg];
            const float g  = wsro[4096 + (pg >> 2)];
            const float cs = cosf(th), sn = sinf(th);
            float h0 = 0.f, h1 = 0.f;
            float* col = Ut + (cc*16)*72 + 2*pp;
            #pragma unroll
            for (int i = 0; i < CHUNK; ++i) {
                float a = col[i*72], b = col[i*72 + 1];
                float n0v = g*(cs*h0 - sn*h1) + a;
                float n1v = g*(sn*h0 + cs*h1) + b;
                col[i*72] = n0v; col[i*72 + 1] = n1v;
                h0 = n0v; h1 = n1v;
            }
            E[(size_t)(mt*4 + cc)*512 + 2*pg]     = h0;
            E[(size_t)(mt*4 + cc)*512 + 2*pg + 1] = h1;
        }
        __syncthreads();
        const int row = tid >> 2, cseg = (tid & 3) * 16;
        #pragma unroll
        for (int j = 0; j < 4; ++j) {
            float4 v = *reinterpret_cast<const float4*>(&Ut[row*72 + cseg + 4*j]);
            *reinterpret_cast<float4*>(Cout + (size_t)(m0 + row)*512 + n0 + cseg + 4*j) = v;
        }
    } else {
        // ---- D*x epilogue ----
        #pragma unroll
        for (int im = 0; im < 2; ++im) {
            #pragma unroll
            for (int in = 0; in < 2; ++in) {
                f32x4 v = (im == 0) ? (in == 0 ? acc00 : acc01)
                                    : (in == 0 ? acc10 : acc11);
                const int row0 = m0 + wm*32 + im*16 + lc*4;
                const int col  = n0 + wn*32 + in*16 + lr;
                const float dv = Dvec[col];
                #pragma unroll
                for (int rg = 0; rg < 4; ++rg) {
                    const int t = row0 + rg;
                    float xv = bf2f(XT[(size_t)t*1024 + col]) + bf2f(XT[(size_t)t*1024 + 512 + col]);
                    Cout[(size_t)t*512 + col] = v[rg] + dv*xv;
                }
            }
        }
    }
}

// ---------------------------------------------------------------------------
// Kernel 4: wave-parallel carry. One wave per pair p; lane l owns chunks
// 4l..4l+3. Chunk-step operator L = gamma^16 R(16*theta); scan multipliers
// L^{4*2^d} computed in closed form (fp64). Also emits TAB in closed form.
__global__ void k_carry(const float* __restrict__ E, float* __restrict__ S,
                        float* __restrict__ TAB,
                        const float* __restrict__ theta_log,
                        const float* __restrict__ gamma_log) {
    const int w = threadIdx.x >> 6, l = threadIdx.x & 63;
    const int p = blockIdx.x*4 + w;
    const double th = exp((double)theta_log[p]);
    const double ed = exp((double)gamma_log[p >> 2]);

    if (l < CHUNK) {   // TAB[i] = gamma^{i+1} * (cos,sin)((i+1)theta)
        double a = (double)(l + 1) * th;
        double g = exp(-(double)(l + 1) * ed);
        TAB[((size_t)l*256 + p)*2 + 0] = (float)(g * cos(a));
        TAB[((size_t)l*256 + p)*2 + 1] = (float)(g * sin(a));
    }

    const double a16 = 16.0*th, g16 = exp(-16.0*ed);
    const float Lc = (float)(g16*cos(a16)), Ls = (float)(g16*sin(a16));

    const float* Ep = E + 2*p;
    float2 e0 = *reinterpret_cast<const float2*>(Ep + (size_t)(4*l + 0)*512);
    float2 e1 = *reinterpret_cast<const float2*>(Ep + (size_t)(4*l + 1)*512);
    float2 e2 = *reinterpret_cast<const float2*>(Ep + (size_t)(4*l + 2)*512);
    float2 e3 = *reinterpret_cast<const float2*>(Ep + (size_t)(4*l + 3)*512);

    float2 v = e0;
    v = make_float2(Lc*v.x - Ls*v.y + e1.x, Ls*v.x + Lc*v.y + e1.y);
    v = make_float2(Lc*v.x - Ls*v.y + e2.x, Ls*v.x + Lc*v.y + e2.y);
    v = make_float2(Lc*v.x - Ls*v.y + e3.x, Ls*v.x + Lc*v.y + e3.y);

    #pragma unroll
    for (int d = 0; d < 6; ++d) {
        const int sh = 1 << d;
        const double aa = 64.0 * (double)sh * th;
        const double gg = exp(-64.0 * (double)sh * ed);
        const float Mc = (float)(gg*cos(aa)), Ms = (float)(gg*sin(aa));
        float px = __shfl_up(v.x, sh, 64);
        float py = __shfl_up(v.y, sh, 64);
        if (l >= sh) {
            v.x += Mc*px - Ms*py;
            v.y += Ms*px + Mc*py;
        }
    }

    float sx = __shfl_up(v.x, 1, 64), sy = __shfl_up(v.y, 1, 64);
    float2 s = (l == 0) ? make_float2(0.f, 0.f) : make_float2(sx, sy);
    float* Sp = S + 2*p;
    *reinterpret_cast<float2*>(Sp + (size_t)(4*l + 0)*512) = s;
    s = make_float2(Lc*s.x - Ls*s.y + e0.x, Ls*s.x + Lc*s.y + e0.y);
    *reinterpret_cast<float2*>(Sp + (size_t)(4*l + 1)*512) = s;
    s = make_float2(Lc*s.x - Ls*s.y + e1.x, Ls*s.x + Lc*s.y + e1.y);
    *reinterpret_cast<float2*>(Sp + (size_t)(4*l + 2)*512) = s;
    s = make_float2(Lc*s.x - Ls*s.y + e2.x, Ls*s.x + Lc*s.y + e2.y);
    *reinterpret_cast<float2*>(Sp + (size_t)(4*l + 3)*512) = s;
}

// ---------------------------------------------------------------------------
extern "C" void kernel_launch(void* const* d_in, const int* in_sizes, int n_in,
                              void* d_out, int out_size, void* d_ws, size_t ws_size,
                              hipStream_t stream) {
    const float* X  = (const float*)d_in[0];  // (8,1,512,1,4096); batch 0 = first 2M floats
    const float* th = (const float*)d_in[1];
    const float* P  = (const float*)d_in[2];
    const float* Bm = (const float*)d_in[3];
    const float* C  = (const float*)d_in[4];
    const float* Dv = (const float*)d_in[5];
    const float* gl = (const float*)d_in[6];
    char* wsb = (char*)d_ws;
    float* ws   = (float*)wsb;
    u16*   W1pk = (u16*)(wsb + 32768);
    u16*   CEpk = (u16*)(wsb + 1081344);
    u16*   XTpk = (u16*)(wsb + 2129920);
    float* U    = (float*)(wsb + 10518528);
    float* E    = (float*)(wsb + 18907136);
    float* S    = (float*)(wsb + 19431424);
    float* TAB  = (float*)(wsb + 19955712);
    float* out  = (float*)d_out;

    k_pre<<<576, 256, 0, stream>>>(X, XTpk, P, Bm, th, gl, ws);
    k_proj<<<2048, 256, 0, stream>>>(Bm, C, ws, W1pk, CEpk);
    k_gemm<0><<<512, 256, 0, stream>>>(XTpk, (const float*)0, W1pk, U, XTpk, Dv, ws, E, S, TAB);
    k_carry<<<64, 256, 0, stream>>>(E, S, TAB, th, gl);
    k_gemm<1><<<512, 256, 0, stream>>>((const u16*)0, U, CEpk, out, XTpk, Dv, ws, E, S, TAB);
}